// Round 10
// baseline (294.794 us; speedup 1.0000x reference)
//
#include <hip/hip_runtime.h>
#include <stdint.h>

typedef unsigned short u16;
typedef unsigned int u32;
typedef __attribute__((ext_vector_type(8))) short short8;    // 8 bf16 (4 VGPRs)
typedef __attribute__((ext_vector_type(4))) float f32x4;
typedef __attribute__((ext_vector_type(16))) float f32x16;
typedef __attribute__((ext_vector_type(4))) unsigned short u16x4;

#define DEV static __device__ __forceinline__

DEV float bf2f(u16 b) { return __uint_as_float(((uint32_t)b) << 16); }
DEV u16 f2bf(float f) {
  uint32_t u = __float_as_uint(f);
  u += 0x7FFFu + ((u >> 16) & 1u);   // round-to-nearest-even
  return (u16)(u >> 16);
}
DEV void gld16(const u16* gsrc, u16* ldsdst) {
  __builtin_amdgcn_global_load_lds((const __attribute__((address_space(1))) void*)gsrc,
                                   (__attribute__((address_space(3))) void*)ldsdst, 16, 0, 0);
}
#define MFMA16(a, b, c) __builtin_amdgcn_mfma_f32_16x16x32_bf16(a, b, c, 0, 0, 0)
#define MFMA32(a, b, c) __builtin_amdgcn_mfma_f32_32x32x16_bf16(a, b, c, 0, 0, 0)

#define WAITVM8() asm volatile("s_waitcnt vmcnt(8)" ::: "memory")
#define WAITVM0() asm volatile("s_waitcnt vmcnt(0)" ::: "memory")

#if __has_builtin(__builtin_amdgcn_exp2f)
DEV float fexp2(float x) { return __builtin_amdgcn_exp2f(x); }
#else
DEV float fexp2(float x) { return exp2f(x); }
#endif

DEV u32 cvtpk(float lo, float hi) {
  u32 r;
  asm("v_cvt_pk_bf16_f32 %0, %1, %2" : "=v"(r) : "v"(lo), "v"(hi));
  return r;
}

// ---------------------------------------------------------------------------
// fp32 -> bf16 conversion: x (8192x1024) + Wq,Wk,Wv,Wo (1024x1024 each)
// ---------------------------------------------------------------------------
__global__ __launch_bounds__(256) void k_convert(
    const float* __restrict__ x, const float* __restrict__ wq, const float* __restrict__ wk,
    const float* __restrict__ wv, const float* __restrict__ wo, u16* __restrict__ ws)
{
  int bid = blockIdx.x, t = threadIdx.x;
  const float* src; u16* dst; size_t off;
  if (bid < 8192) { src = x; dst = ws; off = (size_t)bid * 1024; }
  else {
    int r = bid - 8192; int sel = r >> 10; int lb = r & 1023;
    src = sel == 0 ? wq : sel == 1 ? wk : sel == 2 ? wv : wo;
    dst = ws + 8388608u + (size_t)sel * 1048576u;
    off = (size_t)lb * 1024;
  }
  size_t e = off + (size_t)t * 4;
  f32x4 v = *(const f32x4*)(src + e);
  u16x4 o;
  o.x = f2bf(v.x); o.y = f2bf(v.y); o.z = f2bf(v.z); o.w = f2bf(v.w);
  *(u16x4*)(dst + e) = o;
}

// ---------------------------------------------------------------------------
// Shared GEMM main loop — R3/R8-proven single-buffered form (16KB LDS)
// ---------------------------------------------------------------------------
DEV void gemm_mainloop(const u16* __restrict__ A, const u16* __restrict__ B,
                       int m0, int n0, u16* As, u16* Bs, f32x4 acc[4][4])
{
  const int tid = threadIdx.x, lane = tid & 63, w = tid >> 6;
  const int fr = lane & 15, g = lane >> 4;
  const int wm = w >> 1, wn = w & 1;

  const int rowA0 = (w * 2 + 0) * 16 + (lane >> 2);
  const int rowA1 = (w * 2 + 1) * 16 + (lane >> 2);
  const int ci = lane & 3;
  const u16* ga0 = A + (size_t)(m0 + rowA0) * 1024 + ((ci ^ (rowA0 & 3)) << 3);
  const u16* ga1 = A + (size_t)(m0 + rowA1) * 1024 + ((ci ^ (rowA1 & 3)) << 3);
  const u16* gb0 = B + (size_t)(n0 + rowA0) * 1024 + ((ci ^ (rowA0 & 3)) << 3);
  const u16* gb1 = B + (size_t)(n0 + rowA1) * 1024 + ((ci ^ (rowA1 & 3)) << 3);
  u16* lA0 = As + (w * 2 + 0) * 512;
  u16* lA1 = As + (w * 2 + 1) * 512;
  u16* lB0 = Bs + (w * 2 + 0) * 512;
  u16* lB1 = Bs + (w * 2 + 1) * 512;

  int raf[4], rbf[4];
#pragma unroll
  for (int i = 0; i < 4; ++i) {
    int rA = wm * 64 + i * 16 + fr;
    raf[i] = rA * 32 + ((g ^ (rA & 3)) << 3);
    int rB = wn * 64 + i * 16 + fr;
    rbf[i] = rB * 32 + ((g ^ (rB & 3)) << 3);
  }

  for (int k0 = 0; k0 < 1024; k0 += 32) {
    __syncthreads();
    gld16(ga0 + k0, lA0);
    gld16(ga1 + k0, lA1);
    gld16(gb0 + k0, lB0);
    gld16(gb1 + k0, lB1);
    __syncthreads();
    short8 af[4], bf[4];
#pragma unroll
    for (int i = 0; i < 4; ++i) af[i] = *(const short8*)&As[raf[i]];
#pragma unroll
    for (int i = 0; i < 4; ++i) bf[i] = *(const short8*)&Bs[rbf[i]];
#pragma unroll
    for (int mi = 0; mi < 4; ++mi)
#pragma unroll
      for (int ni = 0; ni < 4; ++ni)
        acc[mi][ni] = MFMA16(af[mi], bf[ni], acc[mi][ni]);
  }
}

// ---------------------------------------------------------------------------
// QKV projection. Q written *0.125*log2(e) (folds attention scale + exp2 domain)
// ---------------------------------------------------------------------------
__global__ __launch_bounds__(256) void k_gemm_qkv(
    const u16* __restrict__ xb, const u16* __restrict__ wqb, const u16* __restrict__ wkb,
    const u16* __restrict__ wvb, const float* __restrict__ bq, const float* __restrict__ bk,
    const float* __restrict__ bv, u16* __restrict__ Qg, u16* __restrict__ Kg,
    u16* __restrict__ Vtg)
{
  __shared__ u16 As[128 * 32], Bs[128 * 32];
  const int mb = blockIdx.x, nb_all = blockIdx.y;
  const int mat = nb_all >> 3, nb = nb_all & 7;
  const u16* W = mat == 0 ? wqb : (mat == 1 ? wkb : wvb);
  const float* bias = mat == 0 ? bq : (mat == 1 ? bk : bv);
  const int m0 = mb * 128, n0 = nb * 128;

  f32x4 acc[4][4];
  f32x4 z = {0.f, 0.f, 0.f, 0.f};
#pragma unroll
  for (int i = 0; i < 4; ++i)
#pragma unroll
    for (int j = 0; j < 4; ++j) acc[i][j] = z;

  gemm_mainloop(xb, W, m0, n0, As, Bs, acc);

  const int tid = threadIdx.x, lane = tid & 63, w = tid >> 6;
  const int fr = lane & 15, g = lane >> 4;
  const int wm = w >> 1, wn = w & 1;

  if (mat <= 1) {
    u16* Og = mat == 0 ? Qg : Kg;
    const float scale = mat == 0 ? 0.18033688011112042f : 1.0f;
#pragma unroll
    for (int mi = 0; mi < 4; ++mi)
#pragma unroll
      for (int ni = 0; ni < 4; ++ni) {
        int n = n0 + wn * 64 + ni * 16 + fr;
        float bv_ = bias[n];
        int h = n >> 6, d = n & 63;
#pragma unroll
        for (int r = 0; r < 4; ++r) {
          int m = m0 + wm * 64 + mi * 16 + 4 * g + r;
          int b = m >> 11, s = m & 2047;
          float v = (acc[mi][ni][r] + bv_) * scale;
          Og[(((size_t)(b * 16 + h)) * 2048 + (size_t)s) * 64 + d] = f2bf(v);
        }
      }
  } else {
#pragma unroll
    for (int mi = 0; mi < 4; ++mi)
#pragma unroll
      for (int ni = 0; ni < 4; ++ni) {
        int n = n0 + wn * 64 + ni * 16 + fr;
        float bv_ = bias[n];
        int h = n >> 6, d = n & 63;
        int mbase = m0 + wm * 64 + mi * 16 + 4 * g;
        int b = mbase >> 11, s0 = mbase & 2047;
        u16x4 pk;
        pk.x = f2bf(acc[mi][ni][0] + bv_);
        pk.y = f2bf(acc[mi][ni][1] + bv_);
        pk.z = f2bf(acc[mi][ni][2] + bv_);
        pk.w = f2bf(acc[mi][ni][3] + bv_);
        *(u16x4*)&Vtg[(((size_t)(b * 16 + h)) * 64 + d) * 2048 + s0] = pk;
      }
  }
}

// ---------------------------------------------------------------------------
// Flash attention — BARRIER-FREE wave-private form. 2 waves/block, each wave
// owns 32 q-rows + private K/V double-buffers (16KB/wave). No __syncthreads
// anywhere: pacing is counted s_waitcnt vmcnt(8) only (8 gld16 per tile).
// Rationale: R3-R9 all convoyed block phases (QK^T | softmax | PV mutually
// exclusive across waves -> MfmaUtil+VALUBusy stuck at 74% non-overlapped).
// Free-running waves let one wave's softmax overlap another's MFMA (m114).
// Math = R9-verified 32x32 form at KVBLK=32 (same frag formulas/exchange).
// WAR safety without barriers: tile t's ds_reads retire (compiler lgkmcnt)
// before t's MFMAs, which precede t+2's stage issue to the same buffer.
// ---------------------------------------------------------------------------
__global__ __launch_bounds__(128) void k_attn(
    const u16* __restrict__ Qg, const u16* __restrict__ Kg, const u16* __restrict__ Vtg,
    u16* __restrict__ headb)
{
  __shared__ u16 KL[2][2][32 * 64];  // [wave][buf] 4KB each
  __shared__ u16 VL[2][2][64 * 32];  // [wave][buf] 4KB each  (32KB total)
  const int tid = threadIdx.x, lane = tid & 63, w = tid >> 6;
  const int l31 = lane & 31, h5 = lane >> 5;
  const bool lo_half = (h5 == 0);
  // XCD swizzle (bijective: 2048 % 8 == 0); one head's 32 q-blocks share an XCD
  const int swz = ((blockIdx.x & 7) << 8) | (blockIdx.x >> 3);
  const int qb = swz & 31, bh = swz >> 5;
  const u16* Qbase = Qg + (size_t)bh * 2048 * 64;
  const u16* Kbase = Kg + (size_t)bh * 2048 * 64;
  const u16* Vbase = Vtg + (size_t)bh * 64 * 2048;

  // staging sources: K call c stages rows c*8..+8 (8x128B), V call c stages
  // d-rows c*16..+16 of the 32-col window (16x64B). XOR-swizzled 16B chunks.
  const int krt = lane >> 3, kci = lane & 7;
  const int koff = ((kci ^ krt) << 3);             // (row&7)==krt
  const int vrt = lane >> 2, vci = lane & 3;
  const int voff = ((vci ^ (vrt & 3)) << 3);       // (row&3)==vrt&3
  const u16* gk0 = Kbase + (size_t)(0 * 8 + krt) * 64 + koff;
  const u16* gk1 = Kbase + (size_t)(1 * 8 + krt) * 64 + koff;
  const u16* gk2 = Kbase + (size_t)(2 * 8 + krt) * 64 + koff;
  const u16* gk3 = Kbase + (size_t)(3 * 8 + krt) * 64 + koff;
  const u16* gv0 = Vbase + (size_t)(0 * 16 + vrt) * 2048 + voff;
  const u16* gv1 = Vbase + (size_t)(1 * 16 + vrt) * 2048 + voff;
  const u16* gv2 = Vbase + (size_t)(2 * 16 + vrt) * 2048 + voff;
  const u16* gv3 = Vbase + (size_t)(3 * 16 + vrt) * 2048 + voff;

  // Q fragments (B-operand): Q[q = l31][d = 16j + 8*h5 + e]
  short8 qf[4];
  {
    const u16* qrow = Qbase + (size_t)(qb * 64 + w * 32 + l31) * 64;
#pragma unroll
    for (int j = 0; j < 4; ++j)
      qf[j] = *(const short8*)&qrow[j * 16 + h5 * 8];
  }

  // compute-side swizzled chunk offsets
  int cjK[4], cjV[2];
#pragma unroll
  for (int j = 0; j < 4; ++j) cjK[j] = ((2 * j + h5) ^ (l31 & 7)) << 3;
#pragma unroll
  for (int s = 0; s < 2; ++s) cjV[s] = ((2 * s + h5) ^ (l31 & 3)) << 3;

  f32x16 po0, po1;
#pragma unroll
  for (int e = 0; e < 16; ++e) { po0[e] = 0.f; po1[e] = 0.f; }
  float mrun = -1e30f, lrun = 0.f;

#define STAGE_TILE(kvn, bufsel)                                  \
  do {                                                           \
    size_t ko_ = (size_t)(kvn) * 2048;                           \
    int vo_ = (kvn) * 32;                                        \
    u16* kd_ = (bufsel) ? KL[w][1] : KL[w][0];                   \
    u16* vd_ = (bufsel) ? VL[w][1] : VL[w][0];                   \
    gld16(gk0 + ko_, kd_ + 0 * 512);                             \
    gld16(gv0 + vo_, vd_ + 0 * 512);                             \
    gld16(gk1 + ko_, kd_ + 1 * 512);                             \
    gld16(gv1 + vo_, vd_ + 1 * 512);                             \
    gld16(gk2 + ko_, kd_ + 2 * 512);                             \
    gld16(gv2 + vo_, vd_ + 2 * 512);                             \
    gld16(gk3 + ko_, kd_ + 3 * 512);                             \
    gld16(gv3 + vo_, vd_ + 3 * 512);                             \
  } while (0)

  STAGE_TILE(0, 0);

  for (int kv = 0; kv < 64; ++kv) {
    const int cur = kv & 1;
    if (kv < 63) {
      STAGE_TILE(kv + 1, cur ^ 1);
      WAITVM8();                       // tile kv's 8 loads retired; next 8 fly
    } else {
      WAITVM0();
    }
    const u16* Kc = cur ? KL[w][1] : KL[w][0];
    const u16* Vc = cur ? VL[w][1] : VL[w][0];

    // S^T(32k x 32q) = K Q^T : 4 chained MFMA32 over d
    f32x16 s0;
#pragma unroll
    for (int e = 0; e < 16; ++e) s0[e] = 0.f;
    __builtin_amdgcn_s_setprio(1);
#pragma unroll
    for (int j = 0; j < 4; ++j) {
      short8 kf = *(const short8*)&Kc[l31 * 64 + cjK[j]];
      s0 = MFMA32(kf, qf[j], s0);
    }
    __builtin_amdgcn_s_setprio(0);

    // online softmax (q = l31 lane-local; partner lane^32 holds other k-rows)
    float mx = s0[0];
#pragma unroll
    for (int e = 1; e < 16; ++e) mx = fmaxf(mx, s0[e]);
    mx = fmaxf(mx, __shfl_xor(mx, 32, 64));
    const bool defer = __all(mx - mrun <= 8.0f);
    const float mnew = defer ? mrun : mx;
#pragma unroll
    for (int e = 0; e < 16; ++e) s0[e] = fexp2(s0[e] - mnew);
    float a0 = 0.f, a1 = 0.f, a2 = 0.f, a3 = 0.f;
#pragma unroll
    for (int e = 0; e < 4; ++e) {
      a0 += s0[4 * e + 0]; a1 += s0[4 * e + 1];
      a2 += s0[4 * e + 2]; a3 += s0[4 * e + 3];
    }
    float rs = (a0 + a1) + (a2 + a3);
    rs += __shfl_xor(rs, 32, 64);
    if (defer) {
      lrun += rs;
    } else {
      float alpha = fexp2(mrun - mnew);
      lrun = lrun * alpha + rs;
      mrun = mnew;
#pragma unroll
      for (int e = 0; e < 16; ++e) { po0[e] *= alpha; po1[e] *= alpha; }
    }

    // PV: O^T += V^T . P^T, 2 k-slices x 2 d-halves
    __builtin_amdgcn_s_setprio(1);
#pragma unroll
    for (int ks = 0; ks < 2; ++ks) {
      u32 lo0 = cvtpk(s0[8 * ks + 0], s0[8 * ks + 1]);
      u32 lo1 = cvtpk(s0[8 * ks + 2], s0[8 * ks + 3]);
      u32 hi0 = cvtpk(s0[8 * ks + 4], s0[8 * ks + 5]);
      u32 hi1 = cvtpk(s0[8 * ks + 6], s0[8 * ks + 7]);
      u32 sent0 = lo_half ? hi0 : lo0;
      u32 sent1 = lo_half ? hi1 : lo1;
      u32 r0 = __shfl_xor(sent0, 32, 64);
      u32 r1 = __shfl_xor(sent1, 32, 64);
      union { u32 u[4]; short8 v; } pf;
      pf.u[0] = lo_half ? lo0 : r0;
      pf.u[1] = lo_half ? lo1 : r1;
      pf.u[2] = lo_half ? r0 : hi0;
      pf.u[3] = lo_half ? r1 : hi1;
      short8 vfa = *(const short8*)&Vc[l31 * 32 + cjV[ks]];
      short8 vfb = *(const short8*)&Vc[1024 + l31 * 32 + cjV[ks]];
      po0 = MFMA32(vfa, pf.v, po0);
      po1 = MFMA32(vfb, pf.v, po1);
    }
    __builtin_amdgcn_s_setprio(0);
  }
#undef STAGE_TILE

  // epilogue: O^T lane owns q=l31; d = dh*32 + (r&3)+8*(r>>2)+4*h5
  const float linv = 1.0f / lrun;
  const int b = bh >> 4, h = bh & 15;
  const int srow = qb * 64 + w * 32 + l31;
  u16* rowp = headb + (size_t)(b * 2048 + srow) * 1024 + h * 64;
#pragma unroll
  for (int i = 0; i < 4; ++i) {
    u16x4 pk;
    pk.x = f2bf(po0[4 * i + 0] * linv);
    pk.y = f2bf(po0[4 * i + 1] * linv);
    pk.z = f2bf(po0[4 * i + 2] * linv);
    pk.w = f2bf(po0[4 * i + 3] * linv);
    *(u16x4*)&rowp[8 * i + 4 * h5] = pk;
    u16x4 pk2;
    pk2.x = f2bf(po1[4 * i + 0] * linv);
    pk2.y = f2bf(po1[4 * i + 1] * linv);
    pk2.z = f2bf(po1[4 * i + 2] * linv);
    pk2.w = f2bf(po1[4 * i + 3] * linv);
    *(u16x4*)&rowp[32 + 8 * i + 4 * h5] = pk2;
  }
}

// ---------------------------------------------------------------------------
// Output projection: proj = head @ Wo^T + bo  (bf16 out)
// ---------------------------------------------------------------------------
__global__ __launch_bounds__(256) void k_gemm_o(
    const u16* __restrict__ headb, const u16* __restrict__ wob, const float* __restrict__ bo,
    u16* __restrict__ projb)
{
  __shared__ u16 As[128 * 32], Bs[128 * 32];
  const int m0 = blockIdx.x * 128, n0 = blockIdx.y * 128;
  f32x4 acc[4][4];
  f32x4 z = {0.f, 0.f, 0.f, 0.f};
#pragma unroll
  for (int i = 0; i < 4; ++i)
#pragma unroll
    for (int j = 0; j < 4; ++j) acc[i][j] = z;

  gemm_mainloop(headb, wob, m0, n0, As, Bs, acc);

  const int tid = threadIdx.x, lane = tid & 63, w = tid >> 6;
  const int fr = lane & 15, g = lane >> 4;
  const int wm = w >> 1, wn = w & 1;
#pragma unroll
  for (int mi = 0; mi < 4; ++mi)
#pragma unroll
    for (int ni = 0; ni < 4; ++ni) {
      int n = n0 + wn * 64 + ni * 16 + fr;
      float bv_ = bo[n];
#pragma unroll
      for (int r = 0; r < 4; ++r) {
        int m = m0 + wm * 64 + mi * 16 + 4 * g + r;
        projb[(size_t)m * 1024 + n] = f2bf(acc[mi][ni][r] + bv_);
      }
    }
}

// ---------------------------------------------------------------------------
// LayerNorm + residual
// ---------------------------------------------------------------------------
__global__ __launch_bounds__(256) void k_ln(
    const u16* __restrict__ projb, const float* __restrict__ x,
    const float* __restrict__ gamma, const float* __restrict__ beta, float* __restrict__ out)
{
  __shared__ float sh1[4], sh2[4];
  const int row = blockIdx.x, t = threadIdx.x, lane = t & 63, w = t >> 6;
  const size_t base = (size_t)row * 1024;
  u16x4 pv = *(const u16x4*)&projb[base + t * 4];
  float v0 = bf2f(pv.x), v1 = bf2f(pv.y), v2 = bf2f(pv.z), v3 = bf2f(pv.w);
  float s1 = v0 + v1 + v2 + v3;
  float s2 = v0 * v0 + v1 * v1 + v2 * v2 + v3 * v3;
  for (int m = 1; m < 64; m <<= 1) {
    s1 += __shfl_xor(s1, m, 64);
    s2 += __shfl_xor(s2, m, 64);
  }
  if (lane == 0) { sh1[w] = s1; sh2[w] = s2; }
  __syncthreads();
  s1 = sh1[0] + sh1[1] + sh1[2] + sh1[3];
  s2 = sh2[0] + sh2[1] + sh2[2] + sh2[3];
  float mu = s1 * (1.0f / 1024.0f);
  float var = s2 * (1.0f / 1024.0f) - mu * mu;
  float rsd = rsqrtf(var + 1e-5f);
  f32x4 xv = *(const f32x4*)&x[base + t * 4];
  f32x4 res;
  int e = t * 4;
  res.x = xv.x + (v0 - mu) * rsd * gamma[e + 0] + beta[e + 0];
  res.y = xv.y + (v1 - mu) * rsd * gamma[e + 1] + beta[e + 1];
  res.z = xv.z + (v2 - mu) * rsd * gamma[e + 2] + beta[e + 2];
  res.w = xv.w + (v3 - mu) * rsd * gamma[e + 3] + beta[e + 3];
  *(f32x4*)&out[base + t * 4] = res;
}

// ---------------------------------------------------------------------------
extern "C" void kernel_launch(void* const* d_in, const int* in_sizes, int n_in,
                              void* d_out, int out_size, void* d_ws, size_t ws_size,
                              hipStream_t stream)
{
  const float* x     = (const float*)d_in[0];
  const float* Wq    = (const float*)d_in[1];
  const float* bq    = (const float*)d_in[2];
  const float* Wk    = (const float*)d_in[3];
  const float* bk    = (const float*)d_in[4];
  const float* Wv    = (const float*)d_in[5];
  const float* bv    = (const float*)d_in[6];
  const float* Wo    = (const float*)d_in[7];
  const float* bo    = (const float*)d_in[8];
  const float* gamma = (const float*)d_in[9];
  const float* beta  = (const float*)d_in[10];
  float* out = (float*)d_out;

  u16* ws   = (u16*)d_ws;
  u16* xb   = ws;                    // 8192*1024
  u16* wqb  = ws + 8388608;
  u16* wkb  = wqb + 1048576;
  u16* wvb  = wkb + 1048576;
  u16* wob  = wvb + 1048576;
  u16* Qg   = wob + 1048576;         // [64][2048][64]
  u16* Kg   = Qg + 8388608;          // [64][2048][64]
  u16* Vtg  = Kg + 8388608;          // [64][64][2048]
  u16* headb = Vtg + 8388608;        // [8192][1024]
  u16* projb = Qg;                   // reuse Q region (dead after attention)

  k_convert<<<12288, 256, 0, stream>>>(x, Wq, Wk, Wv, Wo, ws);
  k_gemm_qkv<<<dim3(64, 24), 256, 0, stream>>>(xb, wqb, wkb, wvb, bq, bk, bv, Qg, Kg, Vtg);
  k_attn<<<dim3(2048), 128, 0, stream>>>(Qg, Kg, Vtg, headb);
  k_gemm_o<<<dim3(64, 8), 256, 0, stream>>>(headb, wob, bo, projb);
  k_ln<<<8192, 256, 0, stream>>>(projb, x, gamma, beta, out);
}